// Round 3
// baseline (243.462 us; speedup 1.0000x reference)
//
#include <hip/hip_runtime.h>
#include <hip/hip_bf16.h>

#define EDIM 128

typedef __attribute__((ext_vector_type(4))) float f32x4;
typedef __attribute__((ext_vector_type(8))) short bf16x8;

// ---- helpers ---------------------------------------------------------------
__device__ __forceinline__ unsigned pack_bf16(float lo, float hi) {
  __hip_bfloat16 l = __float2bfloat16(lo);
  __hip_bfloat16 h = __float2bfloat16(hi);
  unsigned short lu = *reinterpret_cast<unsigned short*>(&l);
  unsigned short hu = *reinterpret_cast<unsigned short*>(&h);
  return (unsigned)lu | ((unsigned)hu << 16);
}
__device__ __forceinline__ float bf_lo(unsigned u) { return __uint_as_float(u << 16); }
__device__ __forceinline__ float bf_hi(unsigned u) { return __uint_as_float(u & 0xffff0000u); }

// ---------------------------------------------------------------------------
// K0: fp32 -> bf16 conversion for emb and W in one launch (grid-stride).
// ---------------------------------------------------------------------------
__global__ __launch_bounds__(256) void convert_bf16_kernel(
    const float* __restrict__ src1, unsigned short* __restrict__ dst1, int n8_1,
    const float* __restrict__ src2, unsigned short* __restrict__ dst2, int n8_2) {
  int total = n8_1 + n8_2;
  for (int i = blockIdx.x * 256 + threadIdx.x; i < total; i += gridDim.x * 256) {
    const float* s;
    unsigned short* d;
    int j;
    if (i < n8_1) { s = src1; d = dst1; j = i; }
    else          { s = src2; d = dst2; j = i - n8_1; }
    const float4* s4 = reinterpret_cast<const float4*>(s) + (size_t)j * 2;
    float4 a = s4[0], b = s4[1];
    uint4 o;
    o.x = pack_bf16(a.x, a.y);
    o.y = pack_bf16(a.z, a.w);
    o.z = pack_bf16(b.x, b.y);
    o.w = pack_bf16(b.z, b.w);
    *(reinterpret_cast<uint4*>(d) + j) = o;
  }
}

// ---------------------------------------------------------------------------
// K1: h1_bf16[n, slice] = mean over 16 neighbors of emb_bf16[nbr, slice].
// Column-sliced for XCD-L2 residency: slice = bid&7 (32B = 16 bf16 columns),
// chunk = bid>>3 covers 128 nodes (2 threads/node, 8 bf16 each).
// Slice table = 3.2 MB -> fits one XCD's 4 MB L2 under round-robin dispatch.
// ---------------------------------------------------------------------------
__global__ __launch_bounds__(256) void hop1_slice_kernel(
    const int* __restrict__ nbr, const unsigned short* __restrict__ src,
    unsigned short* __restrict__ dst, int nNodes) {
  int slice = blockIdx.x & 7;
  int chunk = blockIdx.x >> 3;
  int node = chunk * 128 + (threadIdx.x >> 1);
  if (node >= nNodes) return;
  int half = threadIdx.x & 1;
  int coff = slice * 16 + half * 8;  // bf16 column offset (16B granule)

  const int4* nb4 = reinterpret_cast<const int4*>(nbr) + (size_t)node * 4;
  int4 a = nb4[0], b = nb4[1], c = nb4[2], d = nb4[3];
  int idx[16] = {a.x, a.y, a.z, a.w, b.x, b.y, b.z, b.w,
                 c.x, c.y, c.z, c.w, d.x, d.y, d.z, d.w};

  const unsigned short* base = src + coff;
  float acc[8] = {0.f, 0.f, 0.f, 0.f, 0.f, 0.f, 0.f, 0.f};
#pragma unroll
  for (int m = 0; m < 16; ++m) {
    uint4 v = *reinterpret_cast<const uint4*>(base + (size_t)idx[m] * EDIM);
    acc[0] += bf_lo(v.x); acc[1] += bf_hi(v.x);
    acc[2] += bf_lo(v.y); acc[3] += bf_hi(v.y);
    acc[4] += bf_lo(v.z); acc[5] += bf_hi(v.z);
    acc[6] += bf_lo(v.w); acc[7] += bf_hi(v.w);
  }
  uint4 o;
  o.x = pack_bf16(acc[0] * 0.0625f, acc[1] * 0.0625f);
  o.y = pack_bf16(acc[2] * 0.0625f, acc[3] * 0.0625f);
  o.z = pack_bf16(acc[4] * 0.0625f, acc[5] * 0.0625f);
  o.w = pack_bf16(acc[6] * 0.0625f, acc[7] * 0.0625f);
  *reinterpret_cast<uint4*>(dst + (size_t)node * EDIM + coff) = o;
}

// ---------------------------------------------------------------------------
// K2: X_bf16[b, slice] = mean16(h1_bf16[nbr[inputs[b]], slice])
//                        + emb_bf16[inputs[b], slice].  Same slicing as K1.
// ---------------------------------------------------------------------------
__global__ __launch_bounds__(256) void hop2_slice_kernel(
    const int* __restrict__ inputs, const int* __restrict__ nbr,
    const unsigned short* __restrict__ h1, const unsigned short* __restrict__ embb,
    unsigned short* __restrict__ X, int Bn) {
  int slice = blockIdx.x & 7;
  int chunk = blockIdx.x >> 3;
  int bq = chunk * 128 + (threadIdx.x >> 1);
  if (bq >= Bn) return;
  int half = threadIdx.x & 1;
  int coff = slice * 16 + half * 8;
  int node = inputs[bq];

  const int4* nb4 = reinterpret_cast<const int4*>(nbr) + (size_t)node * 4;
  int4 aa = nb4[0], bb = nb4[1], cc = nb4[2], dd = nb4[3];
  int idx[16] = {aa.x, aa.y, aa.z, aa.w, bb.x, bb.y, bb.z, bb.w,
                 cc.x, cc.y, cc.z, cc.w, dd.x, dd.y, dd.z, dd.w};

  const unsigned short* base = h1 + coff;
  float acc[8] = {0.f, 0.f, 0.f, 0.f, 0.f, 0.f, 0.f, 0.f};
#pragma unroll
  for (int m = 0; m < 16; ++m) {
    uint4 v = *reinterpret_cast<const uint4*>(base + (size_t)idx[m] * EDIM);
    acc[0] += bf_lo(v.x); acc[1] += bf_hi(v.x);
    acc[2] += bf_lo(v.y); acc[3] += bf_hi(v.y);
    acc[4] += bf_lo(v.z); acc[5] += bf_hi(v.z);
    acc[6] += bf_lo(v.w); acc[7] += bf_hi(v.w);
  }
  uint4 se = *reinterpret_cast<const uint4*>(embb + (size_t)node * EDIM + coff);
  uint4 o;
  o.x = pack_bf16(acc[0] * 0.0625f + bf_lo(se.x), acc[1] * 0.0625f + bf_hi(se.x));
  o.y = pack_bf16(acc[2] * 0.0625f + bf_lo(se.y), acc[3] * 0.0625f + bf_hi(se.y));
  o.z = pack_bf16(acc[4] * 0.0625f + bf_lo(se.z), acc[5] * 0.0625f + bf_hi(se.z));
  o.w = pack_bf16(acc[6] * 0.0625f + bf_lo(se.w), acc[7] * 0.0625f + bf_hi(se.w));
  *reinterpret_cast<uint4*>(X + (size_t)bq * EDIM + coff) = o;
}

// ---------------------------------------------------------------------------
// K3: out = relu(X @ W^T + bias) via mfma_f32_16x16x32_bf16.
// 32 rows per wave (2 A-fragment sets), sweeping all F columns.
// C/D layout: col = lane&15, row = (lane>>4)*4 + reg   [m89-verified]
// A/B frag:   row/col = lane&15, k = (lane>>4)*8 + i
// ---------------------------------------------------------------------------
__global__ __launch_bounds__(256) void gemm_mfma_kernel(
    const unsigned short* __restrict__ X, const unsigned short* __restrict__ Wb,
    const float* __restrict__ bias, float* __restrict__ out, int Fdim) {
  int wave = (blockIdx.x * 256 + threadIdx.x) >> 6;
  int lane = threadIdx.x & 63;
  int row0 = wave * 32;
  int r = lane & 15;
  int half = lane >> 4;  // 0..3

  bf16x8 afrag[2][4];
#pragma unroll
  for (int g = 0; g < 2; ++g)
#pragma unroll
    for (int kk = 0; kk < 4; ++kk) {
      uint4 v = *reinterpret_cast<const uint4*>(
          X + (size_t)(row0 + g * 16 + r) * EDIM + kk * 32 + half * 8);
      afrag[g][kk] = *reinterpret_cast<bf16x8*>(&v);
    }

  for (int c0 = 0; c0 < Fdim; c0 += 16) {
    f32x4 acc0 = {0.f, 0.f, 0.f, 0.f};
    f32x4 acc1 = {0.f, 0.f, 0.f, 0.f};
#pragma unroll
    for (int kk = 0; kk < 4; ++kk) {
      uint4 w = *reinterpret_cast<const uint4*>(
          Wb + (size_t)(c0 + r) * EDIM + kk * 32 + half * 8);
      bf16x8 bfrag = *reinterpret_cast<bf16x8*>(&w);
      acc0 = __builtin_amdgcn_mfma_f32_16x16x32_bf16(afrag[0][kk], bfrag, acc0, 0, 0, 0);
      acc1 = __builtin_amdgcn_mfma_f32_16x16x32_bf16(afrag[1][kk], bfrag, acc1, 0, 0, 0);
    }
    float bv = bias[c0 + r];
#pragma unroll
    for (int reg = 0; reg < 4; ++reg) {
      out[(size_t)(row0 + half * 4 + reg) * Fdim + c0 + r] = fmaxf(acc0[reg] + bv, 0.f);
      out[(size_t)(row0 + 16 + half * 4 + reg) * Fdim + c0 + r] = fmaxf(acc1[reg] + bv, 0.f);
    }
  }
}

// ---------------------------------------------------------------------------
extern "C" void kernel_launch(void* const* d_in, const int* in_sizes, int n_in,
                              void* d_out, int out_size, void* d_ws, size_t ws_size,
                              hipStream_t stream) {
  const int* inputs = (const int*)d_in[0];    // [B]
  const int* nbr = (const int*)d_in[1];       // [N,16]
  const float* emb = (const float*)d_in[2];   // [N,128]
  const float* W = (const float*)d_in[3];     // [F,128]
  const float* bias = (const float*)d_in[4];  // [F]
  float* out = (float*)d_out;

  const int B = in_sizes[0];
  const int N = in_sizes[2] / EDIM;
  const int F = in_sizes[4];

  unsigned short* embb = (unsigned short*)d_ws;          // N*128 bf16
  unsigned short* h1 = embb + (size_t)N * EDIM;          // N*128 bf16
  unsigned short* Wb = h1 + (size_t)N * EDIM;            // F*128 bf16
  unsigned short* X = Wb + (size_t)F * EDIM;             // B*128 bf16

  // K0: convert emb and W to bf16 (single launch)
  int n8_emb = N * EDIM / 8;
  int n8_w = F * EDIM / 8;
  convert_bf16_kernel<<<2048, 256, 0, stream>>>(emb, embb, n8_emb, W, Wb, n8_w);

  // K1: hop 1 over all nodes, column-sliced (slice = bid&7 -> XCD-local L2)
  int chunks1 = (N + 127) / 128;
  hop1_slice_kernel<<<chunks1 * 8, 256, 0, stream>>>(nbr, embb, h1, N);

  // K2: hop 2 at query nodes + self embedding, column-sliced
  int chunks2 = (B + 127) / 128;
  hop2_slice_kernel<<<chunks2 * 8, 256, 0, stream>>>(inputs, nbr, h1, embb, X, B);

  // K3: fused GEMM + bias + relu (32 rows/wave)
  int waves = B / 32;
  gemm_mfma_kernel<<<waves / 4, 256, 0, stream>>>(X, Wb, bias, out, F);
}

// Round 4
// 74.649 us; speedup vs baseline: 3.2614x; 3.2614x over previous
//
#include <hip/hip_runtime.h>
#include <hip/hip_bf16.h>

#define EDIM 128

typedef __attribute__((ext_vector_type(4))) float f32x4;
typedef __attribute__((ext_vector_type(2))) float f32x2;
typedef __attribute__((ext_vector_type(8))) short bf16x8;

// ---- helpers ---------------------------------------------------------------
__device__ __forceinline__ unsigned pack_bf16(float lo, float hi) {
  __hip_bfloat16 l = __float2bfloat16(lo);
  __hip_bfloat16 h = __float2bfloat16(hi);
  unsigned short lu = *reinterpret_cast<unsigned short*>(&l);
  unsigned short hu = *reinterpret_cast<unsigned short*>(&h);
  return (unsigned)lu | ((unsigned)hu << 16);
}
__device__ __forceinline__ float bf_lo(unsigned u) { return __uint_as_float(u << 16); }
__device__ __forceinline__ float bf_hi(unsigned u) { return __uint_as_float(u & 0xffff0000u); }

// pack 4 floats -> 4 fp8 e4m3 (one u32)
__device__ __forceinline__ unsigned pack_fp8x4(float a, float b, float c, float d) {
  unsigned u = 0;
  u = __builtin_amdgcn_cvt_pk_fp8_f32(a, b, u, false);  // low word
  u = __builtin_amdgcn_cvt_pk_fp8_f32(c, d, u, true);   // high word
  return u;
}

// ---------------------------------------------------------------------------
// K0: emb fp32 -> fp8 e4m3 table (hop-1 gather table), W fp32 -> bf16.
// Grid-stride; emb items convert 16 floats -> 16B fp8, W items 8 floats -> bf16.
// ---------------------------------------------------------------------------
__global__ __launch_bounds__(256) void convert_kernel(
    const float* __restrict__ emb, unsigned* __restrict__ emb8, int n16_emb,
    const float* __restrict__ W, unsigned short* __restrict__ Wb, int n8_w) {
  int total = n16_emb + n8_w;
  for (int i = blockIdx.x * 256 + threadIdx.x; i < total; i += gridDim.x * 256) {
    if (i < n16_emb) {
      const float4* s4 = reinterpret_cast<const float4*>(emb) + (size_t)i * 4;
      float4 a = s4[0], b = s4[1], c = s4[2], d = s4[3];
      uint4 o;
      o.x = pack_fp8x4(a.x, a.y, a.z, a.w);
      o.y = pack_fp8x4(b.x, b.y, b.z, b.w);
      o.z = pack_fp8x4(c.x, c.y, c.z, c.w);
      o.w = pack_fp8x4(d.x, d.y, d.z, d.w);
      *(reinterpret_cast<uint4*>(emb8) + i) = o;
    } else {
      int j = i - n16_emb;
      const float4* s4 = reinterpret_cast<const float4*>(W) + (size_t)j * 2;
      float4 a = s4[0], b = s4[1];
      uint4 o;
      o.x = pack_bf16(a.x, a.y);
      o.y = pack_bf16(a.z, a.w);
      o.z = pack_bf16(b.x, b.y);
      o.w = pack_bf16(b.z, b.w);
      *(reinterpret_cast<uint4*>(Wb) + j) = o;
    }
  }
}

// ---------------------------------------------------------------------------
// K1: h1_bf16[n] = mean over 16 neighbors of emb_fp8[nbr].
// 16 lanes/node (8B = 8 fp8 per lane -> 128B/row, one L2 line), fp32 accum.
// ---------------------------------------------------------------------------
__global__ __launch_bounds__(256) void hop1_kernel(
    const int* __restrict__ nbr, const unsigned* __restrict__ src8,
    unsigned short* __restrict__ dst, int nNodes) {
  int node = blockIdx.x * 16 + (threadIdx.x >> 4);
  if (node >= nNodes) return;
  int lane = threadIdx.x & 15;

  const int4* nb4 = reinterpret_cast<const int4*>(nbr) + (size_t)node * 4;
  int4 a = nb4[0], b = nb4[1], c = nb4[2], d = nb4[3];
  int idx[16] = {a.x, a.y, a.z, a.w, b.x, b.y, b.z, b.w,
                 c.x, c.y, c.z, c.w, d.x, d.y, d.z, d.w};

  float acc[8] = {0.f, 0.f, 0.f, 0.f, 0.f, 0.f, 0.f, 0.f};
#pragma unroll
  for (int m = 0; m < 16; ++m) {
    // row = 32 u32 of fp8x4; this lane's 8 fp8 = 2 u32
    uint2 v = *reinterpret_cast<const uint2*>(src8 + (size_t)idx[m] * 32 + lane * 2);
    f32x2 p0 = __builtin_amdgcn_cvt_pk_f32_fp8(v.x, false);
    f32x2 p1 = __builtin_amdgcn_cvt_pk_f32_fp8(v.x, true);
    f32x2 p2 = __builtin_amdgcn_cvt_pk_f32_fp8(v.y, false);
    f32x2 p3 = __builtin_amdgcn_cvt_pk_f32_fp8(v.y, true);
    acc[0] += p0.x; acc[1] += p0.y;
    acc[2] += p1.x; acc[3] += p1.y;
    acc[4] += p2.x; acc[5] += p2.y;
    acc[6] += p3.x; acc[7] += p3.y;
  }
  uint4 o;
  o.x = pack_bf16(acc[0] * 0.0625f, acc[1] * 0.0625f);
  o.y = pack_bf16(acc[2] * 0.0625f, acc[3] * 0.0625f);
  o.z = pack_bf16(acc[4] * 0.0625f, acc[5] * 0.0625f);
  o.w = pack_bf16(acc[6] * 0.0625f, acc[7] * 0.0625f);
  *reinterpret_cast<uint4*>(dst + (size_t)node * EDIM + lane * 8) = o;
}

// ---------------------------------------------------------------------------
// K2: X_bf16[b] = mean16(h1_bf16[nbr[inputs[b]]]) + emb_fp32[inputs[b]]
// self-embedding read at full fp32 precision straight from the input table.
// ---------------------------------------------------------------------------
__global__ __launch_bounds__(256) void hop2_kernel(
    const int* __restrict__ inputs, const int* __restrict__ nbr,
    const unsigned short* __restrict__ h1, const float* __restrict__ emb,
    unsigned short* __restrict__ X, int Bn) {
  int b = blockIdx.x * 16 + (threadIdx.x >> 4);
  if (b >= Bn) return;
  int lane = threadIdx.x & 15;
  int node = inputs[b];

  const int4* nb4 = reinterpret_cast<const int4*>(nbr) + (size_t)node * 4;
  int4 aa = nb4[0], bb = nb4[1], cc = nb4[2], dd = nb4[3];
  int idx[16] = {aa.x, aa.y, aa.z, aa.w, bb.x, bb.y, bb.z, bb.w,
                 cc.x, cc.y, cc.z, cc.w, dd.x, dd.y, dd.z, dd.w};

  float acc[8] = {0.f, 0.f, 0.f, 0.f, 0.f, 0.f, 0.f, 0.f};
#pragma unroll
  for (int m = 0; m < 16; ++m) {
    uint4 v = *reinterpret_cast<const uint4*>(h1 + (size_t)idx[m] * EDIM + lane * 8);
    acc[0] += bf_lo(v.x); acc[1] += bf_hi(v.x);
    acc[2] += bf_lo(v.y); acc[3] += bf_hi(v.y);
    acc[4] += bf_lo(v.z); acc[5] += bf_hi(v.z);
    acc[6] += bf_lo(v.w); acc[7] += bf_hi(v.w);
  }
  const float4* se4 = reinterpret_cast<const float4*>(emb + (size_t)node * EDIM + lane * 8);
  float4 s0 = se4[0], s1 = se4[1];
  uint4 o;
  o.x = pack_bf16(acc[0] * 0.0625f + s0.x, acc[1] * 0.0625f + s0.y);
  o.y = pack_bf16(acc[2] * 0.0625f + s0.z, acc[3] * 0.0625f + s0.w);
  o.z = pack_bf16(acc[4] * 0.0625f + s1.x, acc[5] * 0.0625f + s1.y);
  o.w = pack_bf16(acc[6] * 0.0625f + s1.z, acc[7] * 0.0625f + s1.w);
  *reinterpret_cast<uint4*>(X + (size_t)b * EDIM + lane * 8) = o;
}

// ---------------------------------------------------------------------------
// K3: out = relu(X @ W^T + bias) via mfma_f32_16x16x32_bf16.
// 32 rows per wave (2 A-fragment sets), sweeping all F columns.
// C/D layout: col = lane&15, row = (lane>>4)*4 + reg   [m89-verified]
// A/B frag:   row/col = lane&15, k = (lane>>4)*8 + i
// ---------------------------------------------------------------------------
__global__ __launch_bounds__(256) void gemm_mfma_kernel(
    const unsigned short* __restrict__ X, const unsigned short* __restrict__ Wb,
    const float* __restrict__ bias, float* __restrict__ out, int Fdim) {
  int wave = (blockIdx.x * 256 + threadIdx.x) >> 6;
  int lane = threadIdx.x & 63;
  int row0 = wave * 32;
  int r = lane & 15;
  int half = lane >> 4;  // 0..3

  bf16x8 afrag[2][4];
#pragma unroll
  for (int g = 0; g < 2; ++g)
#pragma unroll
    for (int kk = 0; kk < 4; ++kk) {
      uint4 v = *reinterpret_cast<const uint4*>(
          X + (size_t)(row0 + g * 16 + r) * EDIM + kk * 32 + half * 8);
      afrag[g][kk] = *reinterpret_cast<bf16x8*>(&v);
    }

  for (int c0 = 0; c0 < Fdim; c0 += 16) {
    f32x4 acc0 = {0.f, 0.f, 0.f, 0.f};
    f32x4 acc1 = {0.f, 0.f, 0.f, 0.f};
#pragma unroll
    for (int kk = 0; kk < 4; ++kk) {
      uint4 w = *reinterpret_cast<const uint4*>(
          Wb + (size_t)(c0 + r) * EDIM + kk * 32 + half * 8);
      bf16x8 bfrag = *reinterpret_cast<bf16x8*>(&w);
      acc0 = __builtin_amdgcn_mfma_f32_16x16x32_bf16(afrag[0][kk], bfrag, acc0, 0, 0, 0);
      acc1 = __builtin_amdgcn_mfma_f32_16x16x32_bf16(afrag[1][kk], bfrag, acc1, 0, 0, 0);
    }
    float bv = bias[c0 + r];
#pragma unroll
    for (int reg = 0; reg < 4; ++reg) {
      out[(size_t)(row0 + half * 4 + reg) * Fdim + c0 + r] = fmaxf(acc0[reg] + bv, 0.f);
      out[(size_t)(row0 + 16 + half * 4 + reg) * Fdim + c0 + r] = fmaxf(acc1[reg] + bv, 0.f);
    }
  }
}

// ---------------------------------------------------------------------------
extern "C" void kernel_launch(void* const* d_in, const int* in_sizes, int n_in,
                              void* d_out, int out_size, void* d_ws, size_t ws_size,
                              hipStream_t stream) {
  const int* inputs = (const int*)d_in[0];    // [B]
  const int* nbr = (const int*)d_in[1];       // [N,16]
  const float* emb = (const float*)d_in[2];   // [N,128]
  const float* W = (const float*)d_in[3];     // [F,128]
  const float* bias = (const float*)d_in[4];  // [F]
  float* out = (float*)d_out;

  const int B = in_sizes[0];
  const int N = in_sizes[2] / EDIM;
  const int F = in_sizes[4];

  unsigned* emb8 = (unsigned*)d_ws;                          // N*128 fp8 (N*32 u32)
  unsigned short* h1 = (unsigned short*)(emb8 + (size_t)N * 32);  // N*128 bf16
  unsigned short* Wb = h1 + (size_t)N * EDIM;                // F*128 bf16
  unsigned short* X = Wb + (size_t)F * EDIM;                 // B*128 bf16

  // K0: emb -> fp8 table, W -> bf16
  int n16_emb = N * EDIM / 16;
  int n8_w = F * EDIM / 8;
  convert_kernel<<<2048, 256, 0, stream>>>(emb, emb8, n16_emb, W, Wb, n8_w);

  // K1: hop 1 over all nodes (fp8 gather, bf16 output)
  hop1_kernel<<<(N + 15) / 16, 256, 0, stream>>>(nbr, emb8, h1, N);

  // K2: hop 2 at query nodes + fp32 self embedding, pack X bf16
  hop2_kernel<<<(B + 15) / 16, 256, 0, stream>>>(inputs, nbr, h1, emb, X, B);

  // K3: fused GEMM + bias + relu (32 rows/wave)
  int waves = B / 32;
  gemm_mfma_kernel<<<waves / 4, 256, 0, stream>>>(X, Wb, bias, out, F);
}

// Round 5
// 67.731 us; speedup vs baseline: 3.5945x; 1.1021x over previous
//
#include <hip/hip_runtime.h>
#include <hip/hip_bf16.h>

#define EDIM 128

typedef __attribute__((ext_vector_type(4))) float f32x4;
typedef __attribute__((ext_vector_type(2))) float f32x2;
typedef __attribute__((ext_vector_type(8))) short bf16x8;

// ---- helpers ---------------------------------------------------------------
__device__ __forceinline__ unsigned pack_bf16(float lo, float hi) {
  __hip_bfloat16 l = __float2bfloat16(lo);
  __hip_bfloat16 h = __float2bfloat16(hi);
  unsigned short lu = *reinterpret_cast<unsigned short*>(&l);
  unsigned short hu = *reinterpret_cast<unsigned short*>(&h);
  return (unsigned)lu | ((unsigned)hu << 16);
}
__device__ __forceinline__ float bf_lo(unsigned u) { return __uint_as_float(u << 16); }
__device__ __forceinline__ float bf_hi(unsigned u) { return __uint_as_float(u & 0xffff0000u); }

// pack 4 floats -> 4 fp8 e4m3 (one u32)
__device__ __forceinline__ unsigned pack_fp8x4(float a, float b, float c, float d) {
  unsigned u = 0;
  u = __builtin_amdgcn_cvt_pk_fp8_f32(a, b, u, false);  // low word
  u = __builtin_amdgcn_cvt_pk_fp8_f32(c, d, u, true);   // high word
  return u;
}

// ---------------------------------------------------------------------------
// K0: emb fp32 -> fp8 e4m3 table (hop-1 gather table), W fp32 -> bf16.
// ---------------------------------------------------------------------------
__global__ __launch_bounds__(256) void convert_kernel(
    const float* __restrict__ emb, unsigned* __restrict__ emb8, int n16_emb,
    const float* __restrict__ W, unsigned short* __restrict__ Wb, int n8_w) {
  int total = n16_emb + n8_w;
  for (int i = blockIdx.x * 256 + threadIdx.x; i < total; i += gridDim.x * 256) {
    if (i < n16_emb) {
      const float4* s4 = reinterpret_cast<const float4*>(emb) + (size_t)i * 4;
      float4 a = s4[0], b = s4[1], c = s4[2], d = s4[3];
      uint4 o;
      o.x = pack_fp8x4(a.x, a.y, a.z, a.w);
      o.y = pack_fp8x4(b.x, b.y, b.z, b.w);
      o.z = pack_fp8x4(c.x, c.y, c.z, c.w);
      o.w = pack_fp8x4(d.x, d.y, d.z, d.w);
      *(reinterpret_cast<uint4*>(emb8) + i) = o;
    } else {
      int j = i - n16_emb;
      const float4* s4 = reinterpret_cast<const float4*>(W) + (size_t)j * 2;
      float4 a = s4[0], b = s4[1];
      uint4 o;
      o.x = pack_bf16(a.x, a.y);
      o.y = pack_bf16(a.z, a.w);
      o.z = pack_bf16(b.x, b.y);
      o.w = pack_bf16(b.z, b.w);
      *(reinterpret_cast<uint4*>(Wb) + j) = o;
    }
  }
}

// ---------------------------------------------------------------------------
// K1: h1_fp8[n] = mean over 16 neighbors of emb_fp8[nbr].
// 16 lanes/node (8B = 8 fp8 per lane -> 128B/row = one L2 line), fp32 accum,
// fp8 output (halves K1 write and K2's random gather bytes).
// ---------------------------------------------------------------------------
__global__ __launch_bounds__(256) void hop1_kernel(
    const int* __restrict__ nbr, const unsigned* __restrict__ src8,
    unsigned* __restrict__ dst8, int nNodes) {
  int node = blockIdx.x * 16 + (threadIdx.x >> 4);
  if (node >= nNodes) return;
  int lane = threadIdx.x & 15;

  const int4* nb4 = reinterpret_cast<const int4*>(nbr) + (size_t)node * 4;
  int4 a = nb4[0], b = nb4[1], c = nb4[2], d = nb4[3];
  int idx[16] = {a.x, a.y, a.z, a.w, b.x, b.y, b.z, b.w,
                 c.x, c.y, c.z, c.w, d.x, d.y, d.z, d.w};

  float acc[8] = {0.f, 0.f, 0.f, 0.f, 0.f, 0.f, 0.f, 0.f};
#pragma unroll
  for (int m = 0; m < 16; ++m) {
    uint2 v = *reinterpret_cast<const uint2*>(src8 + (size_t)idx[m] * 32 + lane * 2);
    f32x2 p0 = __builtin_amdgcn_cvt_pk_f32_fp8(v.x, false);
    f32x2 p1 = __builtin_amdgcn_cvt_pk_f32_fp8(v.x, true);
    f32x2 p2 = __builtin_amdgcn_cvt_pk_f32_fp8(v.y, false);
    f32x2 p3 = __builtin_amdgcn_cvt_pk_f32_fp8(v.y, true);
    acc[0] += p0.x; acc[1] += p0.y;
    acc[2] += p1.x; acc[3] += p1.y;
    acc[4] += p2.x; acc[5] += p2.y;
    acc[6] += p3.x; acc[7] += p3.y;
  }
  uint2 o;
  o.x = pack_fp8x4(acc[0] * 0.0625f, acc[1] * 0.0625f, acc[2] * 0.0625f, acc[3] * 0.0625f);
  o.y = pack_fp8x4(acc[4] * 0.0625f, acc[5] * 0.0625f, acc[6] * 0.0625f, acc[7] * 0.0625f);
  *reinterpret_cast<uint2*>(dst8 + (size_t)node * 32 + lane * 2) = o;
}

// ---------------------------------------------------------------------------
// K2: X_bf16[b] = mean16(h1_fp8[nbr[inputs[b]]]) + emb_fp32[inputs[b]]
// self-embedding read at full fp32 precision straight from the input table.
// ---------------------------------------------------------------------------
__global__ __launch_bounds__(256) void hop2_kernel(
    const int* __restrict__ inputs, const int* __restrict__ nbr,
    const unsigned* __restrict__ h1_8, const float* __restrict__ emb,
    unsigned short* __restrict__ X, int Bn) {
  int b = blockIdx.x * 16 + (threadIdx.x >> 4);
  if (b >= Bn) return;
  int lane = threadIdx.x & 15;
  int node = inputs[b];

  const int4* nb4 = reinterpret_cast<const int4*>(nbr) + (size_t)node * 4;
  int4 aa = nb4[0], bb = nb4[1], cc = nb4[2], dd = nb4[3];
  int idx[16] = {aa.x, aa.y, aa.z, aa.w, bb.x, bb.y, bb.z, bb.w,
                 cc.x, cc.y, cc.z, cc.w, dd.x, dd.y, dd.z, dd.w};

  float acc[8] = {0.f, 0.f, 0.f, 0.f, 0.f, 0.f, 0.f, 0.f};
#pragma unroll
  for (int m = 0; m < 16; ++m) {
    uint2 v = *reinterpret_cast<const uint2*>(h1_8 + (size_t)idx[m] * 32 + lane * 2);
    f32x2 p0 = __builtin_amdgcn_cvt_pk_f32_fp8(v.x, false);
    f32x2 p1 = __builtin_amdgcn_cvt_pk_f32_fp8(v.x, true);
    f32x2 p2 = __builtin_amdgcn_cvt_pk_f32_fp8(v.y, false);
    f32x2 p3 = __builtin_amdgcn_cvt_pk_f32_fp8(v.y, true);
    acc[0] += p0.x; acc[1] += p0.y;
    acc[2] += p1.x; acc[3] += p1.y;
    acc[4] += p2.x; acc[5] += p2.y;
    acc[6] += p3.x; acc[7] += p3.y;
  }
  const float4* se4 = reinterpret_cast<const float4*>(emb + (size_t)node * EDIM + lane * 8);
  float4 s0 = se4[0], s1 = se4[1];
  uint4 o;
  o.x = pack_bf16(acc[0] * 0.0625f + s0.x, acc[1] * 0.0625f + s0.y);
  o.y = pack_bf16(acc[2] * 0.0625f + s0.z, acc[3] * 0.0625f + s0.w);
  o.z = pack_bf16(acc[4] * 0.0625f + s1.x, acc[5] * 0.0625f + s1.y);
  o.w = pack_bf16(acc[6] * 0.0625f + s1.z, acc[7] * 0.0625f + s1.w);
  *reinterpret_cast<uint4*>(X + (size_t)b * EDIM + lane * 8) = o;
}

// ---------------------------------------------------------------------------
// K3: out = relu(X @ W^T + bias) via mfma_f32_16x16x32_bf16.
// 32 rows per wave (2 A-fragment sets), sweeping all F columns.
// C/D layout: col = lane&15, row = (lane>>4)*4 + reg   [m89-verified]
// A/B frag:   row/col = lane&15, k = (lane>>4)*8 + i
// ---------------------------------------------------------------------------
__global__ __launch_bounds__(256) void gemm_mfma_kernel(
    const unsigned short* __restrict__ X, const unsigned short* __restrict__ Wb,
    const float* __restrict__ bias, float* __restrict__ out, int Fdim) {
  int wave = (blockIdx.x * 256 + threadIdx.x) >> 6;
  int lane = threadIdx.x & 63;
  int row0 = wave * 32;
  int r = lane & 15;
  int half = lane >> 4;  // 0..3

  bf16x8 afrag[2][4];
#pragma unroll
  for (int g = 0; g < 2; ++g)
#pragma unroll
    for (int kk = 0; kk < 4; ++kk) {
      uint4 v = *reinterpret_cast<const uint4*>(
          X + (size_t)(row0 + g * 16 + r) * EDIM + kk * 32 + half * 8);
      afrag[g][kk] = *reinterpret_cast<bf16x8*>(&v);
    }

  for (int c0 = 0; c0 < Fdim; c0 += 16) {
    f32x4 acc0 = {0.f, 0.f, 0.f, 0.f};
    f32x4 acc1 = {0.f, 0.f, 0.f, 0.f};
#pragma unroll
    for (int kk = 0; kk < 4; ++kk) {
      uint4 w = *reinterpret_cast<const uint4*>(
          Wb + (size_t)(c0 + r) * EDIM + kk * 32 + half * 8);
      bf16x8 bfrag = *reinterpret_cast<bf16x8*>(&w);
      acc0 = __builtin_amdgcn_mfma_f32_16x16x32_bf16(afrag[0][kk], bfrag, acc0, 0, 0, 0);
      acc1 = __builtin_amdgcn_mfma_f32_16x16x32_bf16(afrag[1][kk], bfrag, acc1, 0, 0, 0);
    }
    float bv = bias[c0 + r];
#pragma unroll
    for (int reg = 0; reg < 4; ++reg) {
      out[(size_t)(row0 + half * 4 + reg) * Fdim + c0 + r] = fmaxf(acc0[reg] + bv, 0.f);
      out[(size_t)(row0 + 16 + half * 4 + reg) * Fdim + c0 + r] = fmaxf(acc1[reg] + bv, 0.f);
    }
  }
}

// ---------------------------------------------------------------------------
extern "C" void kernel_launch(void* const* d_in, const int* in_sizes, int n_in,
                              void* d_out, int out_size, void* d_ws, size_t ws_size,
                              hipStream_t stream) {
  const int* inputs = (const int*)d_in[0];    // [B]
  const int* nbr = (const int*)d_in[1];       // [N,16]
  const float* emb = (const float*)d_in[2];   // [N,128]
  const float* W = (const float*)d_in[3];     // [F,128]
  const float* bias = (const float*)d_in[4];  // [F]
  float* out = (float*)d_out;

  const int B = in_sizes[0];
  const int N = in_sizes[2] / EDIM;
  const int F = in_sizes[4];

  unsigned* emb8 = (unsigned*)d_ws;                      // N*128 fp8 (N*32 u32)
  unsigned* h1_8 = emb8 + (size_t)N * 32;                // N*128 fp8 (N*32 u32)
  unsigned short* Wb = (unsigned short*)(h1_8 + (size_t)N * 32);  // F*128 bf16
  unsigned short* X = Wb + (size_t)F * EDIM;             // B*128 bf16

  // K0: emb -> fp8 table, W -> bf16
  int n16_emb = N * EDIM / 16;
  int n8_w = F * EDIM / 8;
  convert_kernel<<<4096, 256, 0, stream>>>(emb, emb8, n16_emb, W, Wb, n8_w);

  // K1: hop 1 over all nodes (fp8 gather, fp8 output)
  hop1_kernel<<<(N + 15) / 16, 256, 0, stream>>>(nbr, emb8, h1_8, N);

  // K2: hop 2 at query nodes (fp8 gather) + fp32 self embedding, pack X bf16
  hop2_kernel<<<(B + 15) / 16, 256, 0, stream>>>(inputs, nbr, h1_8, emb, X, B);

  // K3: fused GEMM + bias + relu (32 rows/wave)
  int waves = B / 32;
  gemm_mfma_kernel<<<waves / 4, 256, 0, stream>>>(X, Wb, bias, out, F);
}

// Round 6
// 62.341 us; speedup vs baseline: 3.9053x; 1.0865x over previous
//
#include <hip/hip_runtime.h>
#include <hip/hip_bf16.h>

#define EDIM 128

typedef __attribute__((ext_vector_type(4))) float f32x4;
typedef __attribute__((ext_vector_type(2))) float f32x2;
typedef __attribute__((ext_vector_type(8))) short bf16x8;

// fp4 e2m1 table scale: emb value x -> fp4(x / SCALE); decode multiplies back.
#define FP4_INV_SCALE 1.5f          // 1/(2/3)
#define FP4_SCALE_OVER_16 0.04166667f  // (2/3)/16  (fold mean into dequant)

// ---- helpers ---------------------------------------------------------------
__device__ __forceinline__ unsigned pack_bf16(float lo, float hi) {
  __hip_bfloat16 l = __float2bfloat16(lo);
  __hip_bfloat16 h = __float2bfloat16(hi);
  unsigned short lu = *reinterpret_cast<unsigned short*>(&l);
  unsigned short hu = *reinterpret_cast<unsigned short*>(&h);
  return (unsigned)lu | ((unsigned)hu << 16);
}

// pack 4 floats -> 4 fp8 e4m3 (one u32)
__device__ __forceinline__ unsigned pack_fp8x4(float a, float b, float c, float d) {
  unsigned u = 0;
  u = __builtin_amdgcn_cvt_pk_fp8_f32(a, b, u, false);  // low word
  u = __builtin_amdgcn_cvt_pk_fp8_f32(c, d, u, true);   // high word
  return u;
}

// encode one float -> fp4 e2m1 nibble (round-to-nearest on the e2m1 grid)
__device__ __forceinline__ unsigned enc_fp4(float x) {
  unsigned s = (__float_as_uint(x) >> 31) << 3;
  float m = fabsf(x) * FP4_INV_SCALE;
  unsigned idx = (unsigned)(m > 0.25f) + (m > 0.75f) + (m > 1.25f) + (m > 1.75f)
               + (m > 2.5f) + (m > 3.5f) + (m > 5.0f);
  return idx | s;
}

// decode 8 fp4 nibbles (u32) -> 8 floats in fp4-domain units, TRUE element order.
// nibble j (bits 4j..4j+3) = element j. Route: nibble -> fp8 e4m3 byte via
// v_perm LUT (fp4 values {0,.5,1,1.5,2,3,4,6} are exact in e4m3), then cvt.
__device__ __forceinline__ void dec_fp4x8(unsigned u, float* a) {
  const unsigned LUT_LO = 0x3C383000u;  // mags 0..3 -> e4m3 bytes 0x00,0x30,0x38,0x3C
  const unsigned LUT_HI = 0x4C484440u;  // mags 4..7 -> 0x40,0x44,0x48,0x4C
  unsigned mE = u & 0x07070707u;          // mags of elems 0,2,4,6
  unsigned mO = (u >> 4) & 0x07070707u;   // mags of elems 1,3,5,7
  unsigned sE = (u & 0x08080808u) << 4;   // sign -> byte bit7
  unsigned sO = u & 0x80808080u;
  unsigned E = __builtin_amdgcn_perm(LUT_HI, LUT_LO, mE) | sE;  // bytes e0,e2,e4,e6
  unsigned O = __builtin_amdgcn_perm(LUT_HI, LUT_LO, mO) | sO;  // bytes e1,e3,e5,e7
  f32x2 p;
  p = __builtin_amdgcn_cvt_pk_f32_fp8(E, false); a[0] = p.x; a[2] = p.y;
  p = __builtin_amdgcn_cvt_pk_f32_fp8(E, true);  a[4] = p.x; a[6] = p.y;
  p = __builtin_amdgcn_cvt_pk_f32_fp8(O, false); a[1] = p.x; a[3] = p.y;
  p = __builtin_amdgcn_cvt_pk_f32_fp8(O, true);  a[5] = p.x; a[7] = p.y;
}

// ---------------------------------------------------------------------------
// K0: emb fp32 -> fp4 e2m1 table (hop-1 gather table), W fp32 -> bf16.
// emb items: 8 floats -> one u32 of nibbles.
// ---------------------------------------------------------------------------
__global__ __launch_bounds__(256) void convert_kernel(
    const float* __restrict__ emb, unsigned* __restrict__ emb4, int n8_emb,
    const float* __restrict__ W, unsigned short* __restrict__ Wb, int n8_w) {
  int total = n8_emb + n8_w;
  for (int i = blockIdx.x * 256 + threadIdx.x; i < total; i += gridDim.x * 256) {
    if (i < n8_emb) {
      const float4* s4 = reinterpret_cast<const float4*>(emb) + (size_t)i * 2;
      float4 a = s4[0], b = s4[1];
      unsigned u = enc_fp4(a.x) | (enc_fp4(a.y) << 4) | (enc_fp4(a.z) << 8) |
                   (enc_fp4(a.w) << 12) | (enc_fp4(b.x) << 16) |
                   (enc_fp4(b.y) << 20) | (enc_fp4(b.z) << 24) |
                   (enc_fp4(b.w) << 28);
      emb4[i] = u;
    } else {
      int j = i - n8_emb;
      const float4* s4 = reinterpret_cast<const float4*>(W) + (size_t)j * 2;
      float4 a = s4[0], b = s4[1];
      uint4 o;
      o.x = pack_bf16(a.x, a.y);
      o.y = pack_bf16(a.z, a.w);
      o.z = pack_bf16(b.x, b.y);
      o.w = pack_bf16(b.z, b.w);
      *(reinterpret_cast<uint4*>(Wb) + j) = o;
    }
  }
}

// ---------------------------------------------------------------------------
// K1: h1_fp8[n] = mean over 16 neighbors of emb_fp4[nbr].
// 16 lanes/node, each lane: 1 u32 (8 fp4) per neighbor row; row = 64B.
// fp32 accumulate, fp8 e4m3 output (same h1 layout as round 5).
// ---------------------------------------------------------------------------
__global__ __launch_bounds__(256) void hop1_kernel(
    const int* __restrict__ nbr, const unsigned* __restrict__ src4,
    unsigned* __restrict__ dst8, int nNodes) {
  int node = blockIdx.x * 16 + (threadIdx.x >> 4);
  if (node >= nNodes) return;
  int lane = threadIdx.x & 15;

  const int4* nb4 = reinterpret_cast<const int4*>(nbr) + (size_t)node * 4;
  int4 a = nb4[0], b = nb4[1], c = nb4[2], d = nb4[3];
  int idx[16] = {a.x, a.y, a.z, a.w, b.x, b.y, b.z, b.w,
                 c.x, c.y, c.z, c.w, d.x, d.y, d.z, d.w};

  float acc[8] = {0.f, 0.f, 0.f, 0.f, 0.f, 0.f, 0.f, 0.f};
#pragma unroll
  for (int m = 0; m < 16; ++m) {
    unsigned u = src4[(size_t)idx[m] * 16 + lane];
    float t[8];
    dec_fp4x8(u, t);
#pragma unroll
    for (int j = 0; j < 8; ++j) acc[j] += t[j];
  }
  uint2 o;
  o.x = pack_fp8x4(acc[0] * FP4_SCALE_OVER_16, acc[1] * FP4_SCALE_OVER_16,
                   acc[2] * FP4_SCALE_OVER_16, acc[3] * FP4_SCALE_OVER_16);
  o.y = pack_fp8x4(acc[4] * FP4_SCALE_OVER_16, acc[5] * FP4_SCALE_OVER_16,
                   acc[6] * FP4_SCALE_OVER_16, acc[7] * FP4_SCALE_OVER_16);
  *reinterpret_cast<uint2*>(dst8 + (size_t)node * 32 + lane * 2) = o;
}

// ---------------------------------------------------------------------------
// K2: X_bf16[b] = mean16(h1_fp8[nbr[inputs[b]]]) + emb_fp32[inputs[b]]
// self-embedding read at full fp32 precision straight from the input table.
// ---------------------------------------------------------------------------
__global__ __launch_bounds__(256) void hop2_kernel(
    const int* __restrict__ inputs, const int* __restrict__ nbr,
    const unsigned* __restrict__ h1_8, const float* __restrict__ emb,
    unsigned short* __restrict__ X, int Bn) {
  int b = blockIdx.x * 16 + (threadIdx.x >> 4);
  if (b >= Bn) return;
  int lane = threadIdx.x & 15;
  int node = inputs[b];

  const int4* nb4 = reinterpret_cast<const int4*>(nbr) + (size_t)node * 4;
  int4 aa = nb4[0], bb = nb4[1], cc = nb4[2], dd = nb4[3];
  int idx[16] = {aa.x, aa.y, aa.z, aa.w, bb.x, bb.y, bb.z, bb.w,
                 cc.x, cc.y, cc.z, cc.w, dd.x, dd.y, dd.z, dd.w};

  float acc[8] = {0.f, 0.f, 0.f, 0.f, 0.f, 0.f, 0.f, 0.f};
#pragma unroll
  for (int m = 0; m < 16; ++m) {
    uint2 v = *reinterpret_cast<const uint2*>(h1_8 + (size_t)idx[m] * 32 + lane * 2);
    f32x2 p0 = __builtin_amdgcn_cvt_pk_f32_fp8(v.x, false);
    f32x2 p1 = __builtin_amdgcn_cvt_pk_f32_fp8(v.x, true);
    f32x2 p2 = __builtin_amdgcn_cvt_pk_f32_fp8(v.y, false);
    f32x2 p3 = __builtin_amdgcn_cvt_pk_f32_fp8(v.y, true);
    acc[0] += p0.x; acc[1] += p0.y;
    acc[2] += p1.x; acc[3] += p1.y;
    acc[4] += p2.x; acc[5] += p2.y;
    acc[6] += p3.x; acc[7] += p3.y;
  }
  const float4* se4 = reinterpret_cast<const float4*>(emb + (size_t)node * EDIM + lane * 8);
  float4 s0 = se4[0], s1 = se4[1];
  uint4 o;
  o.x = pack_bf16(acc[0] * 0.0625f + s0.x, acc[1] * 0.0625f + s0.y);
  o.y = pack_bf16(acc[2] * 0.0625f + s0.z, acc[3] * 0.0625f + s0.w);
  o.z = pack_bf16(acc[4] * 0.0625f + s1.x, acc[5] * 0.0625f + s1.y);
  o.w = pack_bf16(acc[6] * 0.0625f + s1.z, acc[7] * 0.0625f + s1.w);
  *reinterpret_cast<uint4*>(X + (size_t)b * EDIM + lane * 8) = o;
}

// ---------------------------------------------------------------------------
// K3: out = relu(X @ W^T + bias) via mfma_f32_16x16x32_bf16.
// 32 rows per wave (2 A-fragment sets), sweeping all F columns.
// C/D layout: col = lane&15, row = (lane>>4)*4 + reg   [m89-verified]
// A/B frag:   row/col = lane&15, k = (lane>>4)*8 + i
// ---------------------------------------------------------------------------
__global__ __launch_bounds__(256) void gemm_mfma_kernel(
    const unsigned short* __restrict__ X, const unsigned short* __restrict__ Wb,
    const float* __restrict__ bias, float* __restrict__ out, int Fdim) {
  int wave = (blockIdx.x * 256 + threadIdx.x) >> 6;
  int lane = threadIdx.x & 63;
  int row0 = wave * 32;
  int r = lane & 15;
  int half = lane >> 4;  // 0..3

  bf16x8 afrag[2][4];
#pragma unroll
  for (int g = 0; g < 2; ++g)
#pragma unroll
    for (int kk = 0; kk < 4; ++kk) {
      uint4 v = *reinterpret_cast<const uint4*>(
          X + (size_t)(row0 + g * 16 + r) * EDIM + kk * 32 + half * 8);
      afrag[g][kk] = *reinterpret_cast<bf16x8*>(&v);
    }

  for (int c0 = 0; c0 < Fdim; c0 += 16) {
    f32x4 acc0 = {0.f, 0.f, 0.f, 0.f};
    f32x4 acc1 = {0.f, 0.f, 0.f, 0.f};
#pragma unroll
    for (int kk = 0; kk < 4; ++kk) {
      uint4 w = *reinterpret_cast<const uint4*>(
          Wb + (size_t)(c0 + r) * EDIM + kk * 32 + half * 8);
      bf16x8 bfrag = *reinterpret_cast<bf16x8*>(&w);
      acc0 = __builtin_amdgcn_mfma_f32_16x16x32_bf16(afrag[0][kk], bfrag, acc0, 0, 0, 0);
      acc1 = __builtin_amdgcn_mfma_f32_16x16x32_bf16(afrag[1][kk], bfrag, acc1, 0, 0, 0);
    }
    float bv = bias[c0 + r];
#pragma unroll
    for (int reg = 0; reg < 4; ++reg) {
      out[(size_t)(row0 + half * 4 + reg) * Fdim + c0 + r] = fmaxf(acc0[reg] + bv, 0.f);
      out[(size_t)(row0 + 16 + half * 4 + reg) * Fdim + c0 + r] = fmaxf(acc1[reg] + bv, 0.f);
    }
  }
}

// ---------------------------------------------------------------------------
extern "C" void kernel_launch(void* const* d_in, const int* in_sizes, int n_in,
                              void* d_out, int out_size, void* d_ws, size_t ws_size,
                              hipStream_t stream) {
  const int* inputs = (const int*)d_in[0];    // [B]
  const int* nbr = (const int*)d_in[1];       // [N,16]
  const float* emb = (const float*)d_in[2];   // [N,128]
  const float* W = (const float*)d_in[3];     // [F,128]
  const float* bias = (const float*)d_in[4];  // [F]
  float* out = (float*)d_out;

  const int B = in_sizes[0];
  const int N = in_sizes[2] / EDIM;
  const int F = in_sizes[4];

  unsigned* emb4 = (unsigned*)d_ws;                      // N*128 fp4 (N*16 u32)
  unsigned* h1_8 = emb4 + (size_t)N * 16;                // N*128 fp8 (N*32 u32)
  unsigned short* Wb = (unsigned short*)(h1_8 + (size_t)N * 32);  // F*128 bf16
  unsigned short* X = Wb + (size_t)F * EDIM;             // B*128 bf16

  // K0: emb -> fp4 table, W -> bf16
  int n8_emb = N * EDIM / 8;
  int n8_w = F * EDIM / 8;
  convert_kernel<<<4096, 256, 0, stream>>>(emb, emb4, n8_emb, W, Wb, n8_w);

  // K1: hop 1 over all nodes (fp4 gather, fp8 output)
  hop1_kernel<<<(N + 15) / 16, 256, 0, stream>>>(nbr, emb4, h1_8, N);

  // K2: hop 2 at query nodes (fp8 gather) + fp32 self embedding, pack X bf16
  hop2_kernel<<<(B + 15) / 16, 256, 0, stream>>>(inputs, nbr, h1_8, emb, X, B);

  // K3: fused GEMM + bias + relu (32 rows/wave)
  int waves = B / 32;
  gemm_mfma_kernel<<<waves / 4, 256, 0, stream>>>(X, Wb, bias, out, F);
}

// Round 7
// 56.568 us; speedup vs baseline: 4.3038x; 1.1021x over previous
//
#include <hip/hip_runtime.h>
#include <hip/hip_bf16.h>

#define EDIM 128

typedef __attribute__((ext_vector_type(4))) float f32x4;
typedef __attribute__((ext_vector_type(2))) float f32x2;
typedef __attribute__((ext_vector_type(8))) short bf16x8;

// fp4 e2m1 scales. emb table: x -> fp4(x * EMB_INV), decode * (2/3).
// h1 table:  x -> fp4(x * H1_INV),  decode * (1/6).
#define EMB_INV 1.5f
#define EMB_S_OVER16 0.04166667f   // (2/3)/16  (fold hop-1 mean into dequant)
#define H1_INV 6.0f
#define H1_S_OVER16 0.010416667f   // (1/6)/16  (fold hop-2 mean into dequant)

// ---- helpers ---------------------------------------------------------------
__device__ __forceinline__ unsigned pack_bf16(float lo, float hi) {
  __hip_bfloat16 l = __float2bfloat16(lo);
  __hip_bfloat16 h = __float2bfloat16(hi);
  unsigned short lu = *reinterpret_cast<unsigned short*>(&l);
  unsigned short hu = *reinterpret_cast<unsigned short*>(&h);
  return (unsigned)lu | ((unsigned)hu << 16);
}

// encode one float -> fp4 e2m1 nibble (round-to-nearest on the e2m1 grid)
__device__ __forceinline__ unsigned enc_fp4(float x, float inv) {
  unsigned s = (__float_as_uint(x) >> 31) << 3;
  float m = fabsf(x) * inv;
  unsigned idx = (unsigned)(m > 0.25f) + (m > 0.75f) + (m > 1.25f) + (m > 1.75f)
               + (m > 2.5f) + (m > 3.5f) + (m > 5.0f);
  return idx | s;
}

// decode 8 fp4 nibbles (u32) -> 8 floats in fp4-grid units, TRUE element order.
// nibble j = element j. Route: nibble -> fp8 e4m3 byte via v_perm LUT
// (fp4 values {0,.5,1,1.5,2,3,4,6} are exact in e4m3), then cvt_pk_f32_fp8.
__device__ __forceinline__ void dec_fp4x8(unsigned u, float* a) {
  const unsigned LUT_LO = 0x3C383000u;
  const unsigned LUT_HI = 0x4C484440u;
  unsigned mE = u & 0x07070707u;
  unsigned mO = (u >> 4) & 0x07070707u;
  unsigned sE = (u & 0x08080808u) << 4;
  unsigned sO = u & 0x80808080u;
  unsigned E = __builtin_amdgcn_perm(LUT_HI, LUT_LO, mE) | sE;  // e0,e2,e4,e6
  unsigned O = __builtin_amdgcn_perm(LUT_HI, LUT_LO, mO) | sO;  // e1,e3,e5,e7
  f32x2 p;
  p = __builtin_amdgcn_cvt_pk_f32_fp8(E, false); a[0] = p.x; a[2] = p.y;
  p = __builtin_amdgcn_cvt_pk_f32_fp8(E, true);  a[4] = p.x; a[6] = p.y;
  p = __builtin_amdgcn_cvt_pk_f32_fp8(O, false); a[1] = p.x; a[3] = p.y;
  p = __builtin_amdgcn_cvt_pk_f32_fp8(O, true);  a[5] = p.x; a[7] = p.y;
}

// ---------------------------------------------------------------------------
// K0: emb fp32 -> fp4 table, W fp32 -> bf16.
// ---------------------------------------------------------------------------
__global__ __launch_bounds__(256) void convert_kernel(
    const float* __restrict__ emb, unsigned* __restrict__ emb4, int n8_emb,
    const float* __restrict__ W, unsigned short* __restrict__ Wb, int n8_w) {
  int total = n8_emb + n8_w;
  for (int i = blockIdx.x * 256 + threadIdx.x; i < total; i += gridDim.x * 256) {
    if (i < n8_emb) {
      const float4* s4 = reinterpret_cast<const float4*>(emb) + (size_t)i * 2;
      float4 a = s4[0], b = s4[1];
      unsigned u = enc_fp4(a.x, EMB_INV) | (enc_fp4(a.y, EMB_INV) << 4) |
                   (enc_fp4(a.z, EMB_INV) << 8) | (enc_fp4(a.w, EMB_INV) << 12) |
                   (enc_fp4(b.x, EMB_INV) << 16) | (enc_fp4(b.y, EMB_INV) << 20) |
                   (enc_fp4(b.z, EMB_INV) << 24) | (enc_fp4(b.w, EMB_INV) << 28);
      emb4[i] = u;
    } else {
      int j = i - n8_emb;
      const float4* s4 = reinterpret_cast<const float4*>(W) + (size_t)j * 2;
      float4 a = s4[0], b = s4[1];
      uint4 o;
      o.x = pack_bf16(a.x, a.y);
      o.y = pack_bf16(a.z, a.w);
      o.z = pack_bf16(b.x, b.y);
      o.w = pack_bf16(b.z, b.w);
      *(reinterpret_cast<uint4*>(Wb) + j) = o;
    }
  }
}

// ---------------------------------------------------------------------------
// K1: h1_fp4[n] = mean over 16 neighbors of emb_fp4[nbr].
// 16 lanes/node, 1 u32 (8 fp4) per lane per neighbor row (64B rows).
// fp32 accumulate, fp4 output (scale 1/6).
// ---------------------------------------------------------------------------
__global__ __launch_bounds__(256) void hop1_kernel(
    const int* __restrict__ nbr, const unsigned* __restrict__ src4,
    unsigned* __restrict__ dst4, int nNodes) {
  int node = blockIdx.x * 16 + (threadIdx.x >> 4);
  if (node >= nNodes) return;
  int lane = threadIdx.x & 15;

  const int4* nb4 = reinterpret_cast<const int4*>(nbr) + (size_t)node * 4;
  int4 a = nb4[0], b = nb4[1], c = nb4[2], d = nb4[3];
  int idx[16] = {a.x, a.y, a.z, a.w, b.x, b.y, b.z, b.w,
                 c.x, c.y, c.z, c.w, d.x, d.y, d.z, d.w};

  float acc[8] = {0.f, 0.f, 0.f, 0.f, 0.f, 0.f, 0.f, 0.f};
#pragma unroll
  for (int m = 0; m < 16; ++m) {
    unsigned u = src4[(size_t)idx[m] * 16 + lane];
    float t[8];
    dec_fp4x8(u, t);
#pragma unroll
    for (int j = 0; j < 8; ++j) acc[j] += t[j];
  }
  unsigned o = 0;
#pragma unroll
  for (int j = 0; j < 8; ++j)
    o |= enc_fp4(acc[j] * EMB_S_OVER16, H1_INV) << (4 * j);
  dst4[(size_t)node * 16 + lane] = o;
}

// ---------------------------------------------------------------------------
// K2K3 fused: hop-2 gather directly in MFMA-fragment layout + GEMM + relu.
// Wave handles 16 queries. Lane (r = lane&15, half = lane>>4).
// Logical-K permutation (same for A and B): afrag[kk] = row elements
// [half*32 + kk*8, +8). So each lane's per-neighbor A-contribution is ONE
// contiguous uint4 (16B) of the 64B fp4 h1 row. No LDS, no X buffer.
// C/D layout: out col = c0 + (lane&15), out row = q0 + (lane>>4)*4 + reg.
// ---------------------------------------------------------------------------
__global__ __launch_bounds__(256) void hop2_gemm_kernel(
    const int* __restrict__ inputs, const int* __restrict__ nbr,
    const unsigned* __restrict__ h1_4, const float* __restrict__ emb,
    const unsigned short* __restrict__ Wb, const float* __restrict__ bias,
    float* __restrict__ out, int Fdim) {
  int wid = threadIdx.x >> 6;
  int lane = threadIdx.x & 63;
  int r = lane & 15;
  int half = lane >> 4;
  int q0 = (blockIdx.x * 4 + wid) * 16;

  int node = inputs[q0 + r];
  const int4* nb4 = reinterpret_cast<const int4*>(nbr) + (size_t)node * 4;
  int4 na = nb4[0], nbv = nb4[1], nc = nb4[2], nd = nb4[3];
  int idx[16] = {na.x, na.y, na.z, na.w, nbv.x, nbv.y, nbv.z, nbv.w,
                 nc.x, nc.y, nc.z, nc.w, nd.x, nd.y, nd.z, nd.w};

  float acc[4][8];
#pragma unroll
  for (int kk = 0; kk < 4; ++kk)
#pragma unroll
    for (int j = 0; j < 8; ++j) acc[kk][j] = 0.f;

#pragma unroll
  for (int m = 0; m < 16; ++m) {
    uint4 v = *reinterpret_cast<const uint4*>(h1_4 + (size_t)idx[m] * 16 + half * 4);
    float t[8];
    dec_fp4x8(v.x, t);
#pragma unroll
    for (int j = 0; j < 8; ++j) acc[0][j] += t[j];
    dec_fp4x8(v.y, t);
#pragma unroll
    for (int j = 0; j < 8; ++j) acc[1][j] += t[j];
    dec_fp4x8(v.z, t);
#pragma unroll
    for (int j = 0; j < 8; ++j) acc[2][j] += t[j];
    dec_fp4x8(v.w, t);
#pragma unroll
    for (int j = 0; j < 8; ++j) acc[3][j] += t[j];
  }

  // finalize: mean*scale + fp32 self-embedding, pack to bf16 fragments
  bf16x8 afrag[4];
#pragma unroll
  for (int kk = 0; kk < 4; ++kk) {
    const float4* se = reinterpret_cast<const float4*>(
        emb + (size_t)node * EDIM + half * 32 + kk * 8);
    float4 s0 = se[0], s1 = se[1];
    float v0 = acc[kk][0] * H1_S_OVER16 + s0.x;
    float v1 = acc[kk][1] * H1_S_OVER16 + s0.y;
    float v2 = acc[kk][2] * H1_S_OVER16 + s0.z;
    float v3 = acc[kk][3] * H1_S_OVER16 + s0.w;
    float v4 = acc[kk][4] * H1_S_OVER16 + s1.x;
    float v5 = acc[kk][5] * H1_S_OVER16 + s1.y;
    float v6 = acc[kk][6] * H1_S_OVER16 + s1.z;
    float v7 = acc[kk][7] * H1_S_OVER16 + s1.w;
    uint4 o;
    o.x = pack_bf16(v0, v1);
    o.y = pack_bf16(v2, v3);
    o.z = pack_bf16(v4, v5);
    o.w = pack_bf16(v6, v7);
    afrag[kk] = *reinterpret_cast<bf16x8*>(&o);
  }

  // GEMM sweep over output features
  for (int c0 = 0; c0 < Fdim; c0 += 16) {
    f32x4 dacc = {0.f, 0.f, 0.f, 0.f};
#pragma unroll
    for (int kk = 0; kk < 4; ++kk) {
      uint4 w = *reinterpret_cast<const uint4*>(
          Wb + (size_t)(c0 + r) * EDIM + half * 32 + kk * 8);
      bf16x8 bfrag = *reinterpret_cast<bf16x8*>(&w);
      dacc = __builtin_amdgcn_mfma_f32_16x16x32_bf16(afrag[kk], bfrag, dacc, 0, 0, 0);
    }
    float bv = bias[c0 + r];
#pragma unroll
    for (int reg = 0; reg < 4; ++reg) {
      out[(size_t)(q0 + half * 4 + reg) * Fdim + c0 + r] = fmaxf(dacc[reg] + bv, 0.f);
    }
  }
}

// ---------------------------------------------------------------------------
extern "C" void kernel_launch(void* const* d_in, const int* in_sizes, int n_in,
                              void* d_out, int out_size, void* d_ws, size_t ws_size,
                              hipStream_t stream) {
  const int* inputs = (const int*)d_in[0];    // [B]
  const int* nbr = (const int*)d_in[1];       // [N,16]
  const float* emb = (const float*)d_in[2];   // [N,128]
  const float* W = (const float*)d_in[3];     // [F,128]
  const float* bias = (const float*)d_in[4];  // [F]
  float* out = (float*)d_out;

  const int B = in_sizes[0];
  const int N = in_sizes[2] / EDIM;
  const int F = in_sizes[4];

  unsigned* emb4 = (unsigned*)d_ws;                      // N*128 fp4 (N*16 u32)
  unsigned* h1_4 = emb4 + (size_t)N * 16;                // N*128 fp4 (N*16 u32)
  unsigned short* Wb = (unsigned short*)(h1_4 + (size_t)N * 16);  // F*128 bf16

  // K0: emb -> fp4 table, W -> bf16
  int n8_emb = N * EDIM / 8;
  int n8_w = F * EDIM / 8;
  convert_kernel<<<4096, 256, 0, stream>>>(emb, emb4, n8_emb, W, Wb, n8_w);

  // K1: hop 1 over all nodes (fp4 gather, fp4 output)
  hop1_kernel<<<(N + 15) / 16, 256, 0, stream>>>(nbr, emb4, h1_4, N);

  // K2K3: fused hop-2 gather (fragment layout) + GEMM + bias + relu
  int blocks = B / 64;  // 4 waves/block, 16 queries/wave
  hop2_gemm_kernel<<<blocks, 256, 0, stream>>>(inputs, nbr, h1_4, emb, Wb, bias,
                                               out, F);
}